// Round 4
// baseline (254.882 us; speedup 1.0000x reference)
//
#include <hip/hip_runtime.h>
#include <hip/hip_bf16.h>

// Binarized-weight 3x3 conv as implicit GEMM, R3 structure (R4 = bugfix):
//   - A (sign(W) as bf16) pre-packed in MFMA fragment order -> K-loop reads
//     A with coalesced global_load_dwordx4, no LDS, no A-stage barriers.
//   - B: one 6-row x 66-col x 64c window of NHWC x_t staged per cc chunk,
//     reused across all 9 (kh,kw) -> 3 barriers per block total.
//   - inner loop per kf: 4 global a-loads + 8 ds_read_b128 + 32 MFMA.
//   - R4 fix: glds16 LDS dest is the wave-uniform base Bw + m*512 shorts
//     (R3 accidentally doubled the stride -> OOB LDS writes -> NaN).

typedef short bf16x8 __attribute__((ext_vector_type(8)));
typedef float f32x4 __attribute__((ext_vector_type(4)));

#define XT_ELEMS (32 * 66 * 66 * 128)
#define XT_BYTES (XT_ELEMS * 2)
#define XT_PAD_BYTES (66 * 128 * 2)   // one spatial row: stage-loop overread pad

__device__ __forceinline__ void glds16(const void* g, const void* l) {
    __builtin_amdgcn_global_load_lds(
        (const __attribute__((address_space(1))) void*)g,
        (__attribute__((address_space(3))) void*)l, 16, 0, 0);
}

// weight OIHW fp32 -> AF in MFMA fragment order:
// flat = ((((j*2+ccI)*2+kf)*16 + o16)*64 + lane)*8 + e
// so a wave-frag (one o16 group, one kf) is 1 KB contiguous, lane-ordered.
// A-operand layout (16x16x32): A[m = lane&15][k = (lane>>4)*8 + e].
__global__ void prep_w_kernel(const float* __restrict__ w,
                              __hip_bfloat16* __restrict__ af) {
    int tid = blockIdx.x * 256 + threadIdx.x;   // 294912 total, exact grid
    int e = tid & 7;
    int l15 = (tid >> 3) & 15;
    int quad = (tid >> 7) & 3;
    int o16 = (tid >> 9) & 15;
    int kf = (tid >> 13) & 1;
    int ccI = (tid >> 14) & 1;
    int j = tid >> 15;                          // 0..8
    int o = o16 * 16 + l15;
    int c = ccI * 64 + kf * 32 + quad * 8 + e;
    float v = w[o * 1152 + c * 9 + j];
    float s = (v > 0.f) ? 1.f : ((v < 0.f) ? -1.f : 0.f);
    af[tid] = __float2bfloat16(s);
}

// x NCHW fp32 -> x_t[n][h+1][w+1][c] bf16 (66x66 spatial, zero halo).
// Coalesced both ways via LDS bounce; halo zeroing folded in.
__global__ void transpose_x_kernel(const float* __restrict__ x,
                                   __hip_bfloat16* __restrict__ xt) {
    __shared__ short tl[64 * 130];   // stride 130: phase-2 reads ~2-way max
    const int t = threadIdx.x;
    const int n = blockIdx.x >> 6;
    const int h = blockIdx.x & 63;
    const float* xp = x + (size_t)n * 524288 + h * 64;
    // phase 1: lanes span w, float2 -> 512 B per wave-load
    for (int i = t; i < 4096; i += 256) {
        int w2 = i & 31, c = i >> 5;
        float2 v = *(const float2*)(xp + c * 4096 + w2 * 2);
        tl[(w2 * 2 + 0) * 130 + c] = (short)__bfloat16_as_ushort(__float2bfloat16(v.x));
        tl[(w2 * 2 + 1) * 130 + c] = (short)__bfloat16_as_ushort(__float2bfloat16(v.y));
    }
    // halo zeroing (disjoint addresses; no barrier needed vs phase 2)
    uint* xtn = (uint*)(xt + (size_t)n * 66 * 66 * 128);
    {
        int row = h + 1;
        if (t < 64)       xtn[(row * 66 + 0) * 64 + t] = 0u;         // col 0
        else if (t < 128) xtn[(row * 66 + 65) * 64 + (t - 64)] = 0u; // col 65
    }
    if (h == 0)  for (int i = t; i < 66 * 64; i += 256) xtn[i] = 0u;
    if (h == 63) for (int i = t; i < 66 * 64; i += 256) xtn[65 * 66 * 64 + i] = 0u;
    __syncthreads();
    // phase 2: lanes span c, uint2 -> 512 B contiguous stores per wave
    uint2* xo = (uint2*)(xt + ((size_t)(n * 66 + h + 1) * 66 + 1) * 128);
    for (int i = t; i < 2048; i += 256) {
        int c4 = i & 31;
        int w = i >> 5;
        uint2 v;
        v.x = *(const uint*)(tl + w * 130 + c4 * 4);
        v.y = *(const uint*)(tl + w * 130 + c4 * 4 + 2);
        xo[w * 32 + c4] = v;
    }
}

// Block: 128 o x 256 px (4 out rows of one n). 4 waves, each 64o x 128px.
// LDS: only the B window (400 cells x 8 segs x 16 B = 51.2 KB), staged once
// per cc chunk. 16B segs XOR-swizzled by (cell&7): frag reads 2-way max.
__global__ __launch_bounds__(256, 2) void gemm_kernel(
    const __hip_bfloat16* __restrict__ xt,
    const __hip_bfloat16* __restrict__ af,
    float* __restrict__ out) {
    __shared__ short Bw[400 * 64];    // 51200 B (396 used + 4 overread pad)

    const int t = threadIdx.x;
    const int lane = t & 63;
    const int wv = t >> 6;
    const int px_blk = blockIdx.x;    // 0..511
    const int o_blk = blockIdx.y;     // 0..1
    const int n = px_blk >> 4;
    const int h0 = (px_blk & 15) * 4;

    const int wo = (wv & 1) * 64;     // wave origin in o
    const int wp = (wv >> 1) * 128;   // wave origin in px
    const int wpr = wp >> 6;          // wave px-row origin (0 or 2)
    const int l15 = lane & 15;
    const int quad = lane >> 4;

    const short* xw = (const short*)xt + (size_t)(n * 66 + h0) * 66 * 128;
    const short* afp = (const short*)af;
    const int o16base = o_blk * 8 + (wv & 1) * 4;

    f32x4 acc[4][8] = {};   // [o frag][px frag]

#pragma unroll 1
    for (int ccI = 0; ccI < 2; ++ccI) {
        if (ccI) __syncthreads();
        // stage 6x66 window x 64c: 3200 segs = 50 full wave-issues.
        // issue m: lanes cover segs s = m*64..m*64+63; seg s -> cell s>>3,
        // physical 16B slot s&7 (holds logical seg (s&7)^(cell&7)).
        // Dest passed to glds16 is the WAVE-UNIFORM base (lane*16B implicit).
#pragma unroll
        for (int m = wv; m < 50; m += 4) {
            int s = m * 64 + lane;
            int cel = s >> 3;
            int q = s & 7;
            int sg = q ^ (cel & 7);
            glds16(xw + cel * 128 + ccI * 64 + sg * 8, Bw + m * 512);
        }
        __syncthreads();
#pragma unroll 1
        for (int kh = 0; kh < 3; ++kh) {
#pragma unroll
            for (int kw = 0; kw < 3; ++kw) {
                const int j = kh * 3 + kw;
#pragma unroll
                for (int kf = 0; kf < 2; ++kf) {
                    bf16x8 a[4], b[8];
#pragma unroll
                    for (int i = 0; i < 4; ++i) {
                        int fragIdx = ((j * 2 + ccI) * 2 + kf) * 16 + o16base + i;
                        a[i] = *(const bf16x8*)(afp + fragIdx * 512 + lane * 8);
                    }
#pragma unroll
                    for (int i = 0; i < 8; ++i) {
                        int cell = (kh + wpr + (i >> 2)) * 66 + (i & 3) * 16 + l15 + kw;
                        int seg = (kf * 4 + quad) ^ (cell & 7);
                        b[i] = *(const bf16x8*)(Bw + cell * 64 + seg * 8);
                    }
#pragma unroll
                    for (int i = 0; i < 4; ++i)
#pragma unroll
                        for (int jj = 0; jj < 8; ++jj)
                            acc[i][jj] = __builtin_amdgcn_mfma_f32_16x16x32_bf16(
                                a[i], b[jj], acc[i][jj], 0, 0, 0);
                }
            }
        }
    }

    // Epilogue: C/D layout col=lane&15 (px), row=quad*4+reg (o)
    const int Pbase = px_blk * 256 + wp;
#pragma unroll
    for (int i = 0; i < 4; ++i) {
#pragma unroll
        for (int jj = 0; jj < 8; ++jj) {
            const int P = Pbase + jj * 16 + l15;
            const int hw = P & 4095;
            float* op = out + (size_t)n * 1048576 + hw;
#pragma unroll
            for (int r = 0; r < 4; ++r) {
                const int o = o_blk * 128 + wo + i * 16 + quad * 4 + r;
                op[(size_t)o * 4096] = acc[i][jj][r];
            }
        }
    }
}

extern "C" void kernel_launch(void* const* d_in, const int* in_sizes, int n_in,
                              void* d_out, int out_size, void* d_ws, size_t ws_size,
                              hipStream_t stream) {
    const float* x = (const float*)d_in[0];
    const float* w = (const float*)d_in[1];
    float* out = (float*)d_out;
    __hip_bfloat16* xt = (__hip_bfloat16*)d_ws;
    __hip_bfloat16* af = (__hip_bfloat16*)((char*)d_ws + XT_BYTES + XT_PAD_BYTES);

    prep_w_kernel<<<1152, 256, 0, stream>>>(w, af);
    transpose_x_kernel<<<2048, 256, 0, stream>>>(x, xt);
    gemm_kernel<<<dim3(512, 2), 256, 0, stream>>>(xt, af, out);
}